// Round 4
// baseline (332.120 us; speedup 1.0000x reference)
//
#include <hip/hip_runtime.h>

constexpr int BB = 4, SS = 2048, HH = 1024, NH = 16, HD = 64;
constexpr int M = BB * SS;  // 8192 rows for all GEMMs

typedef short          bf16x8 __attribute__((ext_vector_type(8)));
typedef unsigned short u16x8  __attribute__((ext_vector_type(8)));
typedef float          f32x4  __attribute__((ext_vector_type(4)));

// round-half-up bf16 cvt (differs from RNE only on exact ties)
__device__ __forceinline__ unsigned short f2bf(float f) {
    union { float f; unsigned u; } c; c.f = f;
    return (unsigned short)((c.u + 0x8000u) >> 16);
}
__device__ __forceinline__ unsigned packbf2(float lo, float hi) {
    return (unsigned)f2bf(lo) | ((unsigned)f2bf(hi) << 16);
}
__device__ __forceinline__ u16x8 pack8(const float4& x, const float4& y) {
    u16x8 r = { f2bf(x.x), f2bf(x.y), f2bf(x.z), f2bf(x.w),
                f2bf(y.x), f2bf(y.y), f2bf(y.z), f2bf(y.w) };
    return r;
}

// global -> LDS direct DMA, 16B per lane.
__device__ __forceinline__ void gld_lds16(const unsigned short* g, unsigned short* l) {
    __builtin_amdgcn_global_load_lds(
        (const __attribute__((address_space(1))) unsigned int*)(const void*)g,
        (__attribute__((address_space(3))) unsigned int*)(void*)l,
        16, 0, 0);
}

// Workgroup barrier that drains ONLY LDS (lgkmcnt), leaving global loads in
// flight across the barrier (T4 minimal form).  __syncthreads would drain
// vmcnt(0) and serialize the register prefetch against HBM latency.
__device__ __forceinline__ void ldsbar() {
    __builtin_amdgcn_sched_barrier(0);
    asm volatile("s_waitcnt lgkmcnt(0)" ::: "memory");
    __builtin_amdgcn_s_barrier();
    __builtin_amdgcn_sched_barrier(0);
}

// ---------------------------------------------------------------------------
// Fused prep: z=0 -> X fp32->bf16 (4096 blocks); z=1..4 -> Wq/Wk/Wv/Wp
// fp32 [k][n] -> bf16 transposed [n][k] via 64x64 LDS tiles (256 blocks).
// ---------------------------------------------------------------------------
__global__ __launch_bounds__(256) void prep_k(
    const float* __restrict__ hs,
    const float* __restrict__ Wq, const float* __restrict__ Wk,
    const float* __restrict__ Wv, const float* __restrict__ Wp,
    unsigned short* __restrict__ Xb, unsigned short* __restrict__ WT,
    unsigned short* __restrict__ WTp, const int doWp)
{
    __shared__ __attribute__((aligned(16))) unsigned short T[64][72];

    if (blockIdx.z == 0) {
        const size_t i = ((size_t)blockIdx.x * 256 + threadIdx.x) * 8;
        float4 x0 = *(const float4*)(hs + i);
        float4 x1 = *(const float4*)(hs + i + 4);
        *(u16x8*)(Xb + i) = pack8(x0, x1);
        return;
    }
    if (blockIdx.x >= 256) return;
    const int z = blockIdx.z - 1;
    if (z == 3 && !doWp) return;
    const float* W = (z == 0) ? Wq : (z == 1) ? Wk : (z == 2) ? Wv : Wp;
    unsigned short* D = (z == 3) ? WTp : WT + (size_t)z * HH * HH;

    const int tid = threadIdx.x;
    const int kB = (blockIdx.x & 15) * 64, nB = (blockIdx.x >> 4) * 64;
    const int r = tid >> 2, c0 = (tid & 3) * 16;
#pragma unroll
    for (int j = 0; j < 4; ++j) {
        float4 w = *(const float4*)(W + (size_t)(kB + r) * HH + nB + c0 + j * 4);
        T[c0 + j * 4 + 0][r] = f2bf(w.x);
        T[c0 + j * 4 + 1][r] = f2bf(w.y);
        T[c0 + j * 4 + 2][r] = f2bf(w.z);
        T[c0 + j * 4 + 3][r] = f2bf(w.w);
    }
    __syncthreads();
    *(u16x8*)(D + (size_t)(nB + r) * HH + kB + c0)     = *(const u16x8*)&T[r][c0];
    *(u16x8*)(D + (size_t)(nB + r) * HH + kB + c0 + 8) = *(const u16x8*)&T[r][c0 + 8];
}

// ---------------------------------------------------------------------------
// QKV GEMM, m97 structure: 128x128 tile, BK=32, both operands bf16 staged
// via global_load_lds (width 16), 2 barriers per K-step.  Epilogue restages
// the accumulator through LDS (4 column-chunks) for coalesced vector writes.
// ---------------------------------------------------------------------------
__global__ __launch_bounds__(256) void qkv_gemm(
    const unsigned short* __restrict__ Xb, const unsigned short* __restrict__ WT,
    const float* __restrict__ bq, const float* __restrict__ bk, const float* __restrict__ bv,
    unsigned short* __restrict__ Qd, float* __restrict__ Kd, float* __restrict__ Vd)
{
    const int z = blockIdx.z;
    const unsigned short* Wg = WT + (size_t)z * HH * HH;
    const float* bias = (z == 0) ? bq : (z == 1) ? bk : bv;

    __shared__ __attribute__((aligned(16))) unsigned short SM[2 * 128 * 32];
    unsigned short* As = SM;
    unsigned short* Bs = SM + 128 * 32;

    const int tid  = threadIdx.x;
    const int wave = tid >> 6, lane = tid & 63;
    const int lrow = lane & 15, lq = lane >> 4;
    const int rQ = (wave >> 1) * 64, cQ = (wave & 1) * 64;
    const int mBase = blockIdx.x * 128, nBase = blockIdx.y * 128;

    f32x4 acc[4][4] = {};

    const int srow = lane >> 2, scol = (lane & 3) * 8;
    const int c0 = wave * 2, c1 = wave * 2 + 1;

    const unsigned short* ga0 = Xb + (size_t)(mBase + c0 * 16 + srow) * HH + scol;
    const unsigned short* ga1 = Xb + (size_t)(mBase + c1 * 16 + srow) * HH + scol;
    const unsigned short* gb0 = Wg + (size_t)(nBase + c0 * 16 + srow) * HH + scol;
    const unsigned short* gb1 = Wg + (size_t)(nBase + c1 * 16 + srow) * HH + scol;
    unsigned short* la0 = &As[c0 * 512];
    unsigned short* la1 = &As[c1 * 512];
    unsigned short* lb0 = &Bs[c0 * 512];
    unsigned short* lb1 = &Bs[c1 * 512];

    for (int k0 = 0; k0 < HH; k0 += 32) {
        __syncthreads();  // prior iter's fragment reads done (vmcnt clean here)
        gld_lds16(ga0 + k0, la0);
        gld_lds16(ga1 + k0, la1);
        gld_lds16(gb0 + k0, lb0);
        gld_lds16(gb1 + k0, lb1);
        __syncthreads();  // staging complete (needs the vmcnt drain)

        bf16x8 af[4], bf[4];
#pragma unroll
        for (int i = 0; i < 4; ++i)
            af[i] = *(const bf16x8*)&As[(rQ + i * 16 + lrow) * 32 + lq * 8];
#pragma unroll
        for (int j = 0; j < 4; ++j)
            bf[j] = *(const bf16x8*)&Bs[(cQ + j * 16 + lrow) * 32 + lq * 8];
#pragma unroll
        for (int i = 0; i < 4; ++i)
#pragma unroll
            for (int j = 0; j < 4; ++j)
                acc[i][j] = __builtin_amdgcn_mfma_f32_16x16x32_bf16(af[i], bf[j], acc[i][j], 0, 0, 0);
    }

    // epilogue: LDS-transposed coalesced writes, 4 chunks of 32 n-cols
    float* Cf = (float*)SM;  // [128][32] fp32 view, 16 KB
#pragma unroll
    for (int j = 0; j < 4; ++j) {
        __syncthreads();
        {
            const int c = ((cQ >> 6) << 4) + lrow;
            const int n = nBase + cQ + j * 16 + lrow;
            const float bv = bias[n];
#pragma unroll
            for (int i = 0; i < 4; ++i)
#pragma unroll
                for (int r = 0; r < 4; ++r)
                    Cf[(rQ + i * 16 + lq * 4 + r) * 32 + c] = acc[i][j][r] + bv;
        }
        __syncthreads();
        {
            const int row = tid >> 1, ch = (tid & 1) * 16;
            const int n0 = nBase + (ch ? 64 : 0) + j * 16;
            const int h = n0 >> 6, d0 = n0 & 63;
            const int m = mBase + row;
            const int b = m >> 11, s = m & (SS - 1);
            const size_t base = ((size_t)(b * NH + h) * SS + s) * HD + d0;
            const float* src = &Cf[row * 32 + ch];
            if (z == 0) {
                float4 x0 = *(const float4*)(src);
                float4 x1 = *(const float4*)(src + 4);
                float4 x2 = *(const float4*)(src + 8);
                float4 x3 = *(const float4*)(src + 12);
                *(u16x8*)(Qd + base)     = pack8(x0, x1);
                *(u16x8*)(Qd + base + 8) = pack8(x2, x3);
            } else {
                float* D = (z == 1) ? Kd : Vd;
#pragma unroll
                for (int q = 0; q < 4; ++q)
                    *(float4*)(D + base + q * 4) = *(const float4*)(src + q * 4);
            }
        }
    }
}

// ---------------------------------------------------------------------------
// Output projection, m97 structure + coalesced LDS-staged epilogue.
// ---------------------------------------------------------------------------
__global__ __launch_bounds__(256) void proj_bf(
    const unsigned short* __restrict__ Xc, const unsigned short* __restrict__ WTp,
    const float* __restrict__ bias, float* __restrict__ dst)
{
    __shared__ __attribute__((aligned(16))) unsigned short SM[2 * 128 * 32];
    unsigned short* As = SM;
    unsigned short* Bs = SM + 128 * 32;

    const int tid  = threadIdx.x;
    const int wave = tid >> 6, lane = tid & 63;
    const int lrow = lane & 15, lq = lane >> 4;
    const int rQ = (wave >> 1) * 64, cQ = (wave & 1) * 64;
    const int mBase = blockIdx.x * 128, nBase = blockIdx.y * 128;

    f32x4 acc[4][4] = {};

    const int srow = lane >> 2, scol = (lane & 3) * 8;
    const int c0 = wave * 2, c1 = wave * 2 + 1;

    const unsigned short* ga0 = Xc  + (size_t)(mBase + c0 * 16 + srow) * HH + scol;
    const unsigned short* ga1 = Xc  + (size_t)(mBase + c1 * 16 + srow) * HH + scol;
    const unsigned short* gb0 = WTp + (size_t)(nBase + c0 * 16 + srow) * HH + scol;
    const unsigned short* gb1 = WTp + (size_t)(nBase + c1 * 16 + srow) * HH + scol;
    unsigned short* la0 = &As[c0 * 512];
    unsigned short* la1 = &As[c1 * 512];
    unsigned short* lb0 = &Bs[c0 * 512];
    unsigned short* lb1 = &Bs[c1 * 512];

    for (int k0 = 0; k0 < HH; k0 += 32) {
        __syncthreads();
        gld_lds16(ga0 + k0, la0);
        gld_lds16(ga1 + k0, la1);
        gld_lds16(gb0 + k0, lb0);
        gld_lds16(gb1 + k0, lb1);
        __syncthreads();

        bf16x8 af[4], bf[4];
#pragma unroll
        for (int i = 0; i < 4; ++i)
            af[i] = *(const bf16x8*)&As[(rQ + i * 16 + lrow) * 32 + lq * 8];
#pragma unroll
        for (int j = 0; j < 4; ++j)
            bf[j] = *(const bf16x8*)&Bs[(cQ + j * 16 + lrow) * 32 + lq * 8];
#pragma unroll
        for (int i = 0; i < 4; ++i)
#pragma unroll
            for (int j = 0; j < 4; ++j)
                acc[i][j] = __builtin_amdgcn_mfma_f32_16x16x32_bf16(af[i], bf[j], acc[i][j], 0, 0, 0);
    }

    float* Cf = (float*)SM;
#pragma unroll
    for (int j = 0; j < 4; ++j) {
        __syncthreads();
        {
            const int c = ((cQ >> 6) << 4) + lrow;
            const float bv = bias[nBase + cQ + j * 16 + lrow];
#pragma unroll
            for (int i = 0; i < 4; ++i)
#pragma unroll
                for (int r = 0; r < 4; ++r)
                    Cf[(rQ + i * 16 + lq * 4 + r) * 32 + c] = acc[i][j][r] + bv;
        }
        __syncthreads();
        {
            const int row = tid >> 1, ch = (tid & 1) * 16;
            const int n0 = nBase + (ch ? 64 : 0) + j * 16;
            const float* src = &Cf[row * 32 + ch];
            float* D = dst + (size_t)(mBase + row) * HH + n0;
#pragma unroll
            for (int q = 0; q < 4; ++q)
                *(float4*)(D + q * 4) = *(const float4*)(src + q * 4);
        }
    }
}

// ---------------------------------------------------------------------------
// Fallback output projection (W fp32 transposed in-kernel) for small ws.
// ---------------------------------------------------------------------------
__global__ __launch_bounds__(256) void proj_gemm(
    const unsigned short* __restrict__ X, const float* __restrict__ Wm,
    const float* __restrict__ bias, float* __restrict__ dst)
{
    __shared__ __attribute__((aligned(16))) unsigned short Al[128][40];
    __shared__ __attribute__((aligned(16))) unsigned short Wt[128][40];

    const int tid  = threadIdx.x;
    const int wave = tid >> 6, lane = tid & 63;
    const int lrow = lane & 15, lq = lane >> 4;
    const int rQ = (wave >> 1) * 64, cQ = (wave & 1) * 64;
    const int mBase = blockIdx.x * 128, nBase = blockIdx.y * 128;

    f32x4 acc[4][4] = {};

    const int arow = tid >> 1, acol = (tid & 1) * 16;
    const int wcol = (tid & 15) * 8, wrow = (tid >> 4) * 2;

    const unsigned short* Ap = X + (size_t)(mBase + arow) * HH + acol;
    const float*          Wp = Wm + (size_t)wrow * HH + nBase + wcol;

    u16x8 a0, a1, a0n, a1n;
    float4 w0a, w0b, w1a, w1b, w0an, w0bn, w1an, w1bn;
    a0 = *(const u16x8*)Ap; a1 = *(const u16x8*)(Ap + 8);
    w0a = *(const float4*)(Wp);      w0b = *(const float4*)(Wp + 4);
    w1a = *(const float4*)(Wp + HH); w1b = *(const float4*)(Wp + HH + 4);
    Ap += 32; Wp += (size_t)32 * HH;

    for (int k0 = 0; k0 < HH; k0 += 32) {
        __syncthreads();
        *(u16x8*)&Al[arow][acol]     = a0;
        *(u16x8*)&Al[arow][acol + 8] = a1;
        *(unsigned*)&Wt[wcol + 0][wrow] = packbf2(w0a.x, w1a.x);
        *(unsigned*)&Wt[wcol + 1][wrow] = packbf2(w0a.y, w1a.y);
        *(unsigned*)&Wt[wcol + 2][wrow] = packbf2(w0a.z, w1a.z);
        *(unsigned*)&Wt[wcol + 3][wrow] = packbf2(w0a.w, w1a.w);
        *(unsigned*)&Wt[wcol + 4][wrow] = packbf2(w0b.x, w1b.x);
        *(unsigned*)&Wt[wcol + 5][wrow] = packbf2(w0b.y, w1b.y);
        *(unsigned*)&Wt[wcol + 6][wrow] = packbf2(w0b.z, w1b.z);
        *(unsigned*)&Wt[wcol + 7][wrow] = packbf2(w0b.w, w1b.w);
        if (k0 + 32 < HH) {
            a0n = *(const u16x8*)Ap; a1n = *(const u16x8*)(Ap + 8);
            w0an = *(const float4*)(Wp);      w0bn = *(const float4*)(Wp + 4);
            w1an = *(const float4*)(Wp + HH); w1bn = *(const float4*)(Wp + HH + 4);
            Ap += 32; Wp += (size_t)32 * HH;
        }
        __syncthreads();

        bf16x8 af[4], bf[4];
#pragma unroll
        for (int i = 0; i < 4; ++i) af[i] = *(const bf16x8*)&Al[rQ + i * 16 + lrow][lq * 8];
#pragma unroll
        for (int j = 0; j < 4; ++j) bf[j] = *(const bf16x8*)&Wt[cQ + j * 16 + lrow][lq * 8];
#pragma unroll
        for (int i = 0; i < 4; ++i)
#pragma unroll
            for (int j = 0; j < 4; ++j)
                acc[i][j] = __builtin_amdgcn_mfma_f32_16x16x32_bf16(af[i], bf[j], acc[i][j], 0, 0, 0);

        a0 = a0n; a1 = a1n;
        w0a = w0an; w0b = w0bn; w1a = w1an; w1b = w1bn;
    }

#pragma unroll
    for (int j = 0; j < 4; ++j) {
        int   n  = nBase + cQ + j * 16 + lrow;
        float bv = bias[n];
#pragma unroll
        for (int i = 0; i < 4; ++i)
#pragma unroll
            for (int r = 0; r < 4; ++r) {
                int m = mBase + rQ + i * 16 + lq * 4 + r;
                dst[(size_t)m * HH + n] = acc[i][j][r] + bv;
            }
    }
}

// ---------------------------------------------------------------------------
// Causal flash attention v4: QBLK=256 / 8 waves / KVBLK=64, balanced causal
// pairing.  Loop barriers drain LDS ONLY (ldsbar) so the register prefetch
// of the next K/V tile genuinely stays in flight through compute — the v3
// __syncthreads drained vmcnt(0) and exposed full HBM latency every tile.
// ---------------------------------------------------------------------------
__global__ __launch_bounds__(512, 2) void attn_k(
    const unsigned short* __restrict__ Qb, const float* __restrict__ Kb,
    const float* __restrict__ Vb, unsigned short* __restrict__ ctx)
{
    __shared__ __attribute__((aligned(16))) unsigned short Ps[256][64];  // swizzled
    __shared__ __attribute__((aligned(16))) unsigned short Ks[64][72];
    __shared__ __attribute__((aligned(16))) unsigned short Vt[64][72];   // Vt[d][s^swz]

    const int tid  = threadIdx.x;
    const int wave = tid >> 6, lane = tid & 63;
    const int lrow = lane & 15, lq = lane >> 4;
    const int bh = blockIdx.y;
    const int b = bh >> 4, h = bh & 15;

    const unsigned short* Q = Qb + (size_t)bh * SS * HD;
    const float*          K = Kb + (size_t)bh * SS * HD;
    const float*          V = Vb + (size_t)bh * SS * HD;

    const int ldr = tid >> 3;          // K/V row 0..63
    const int fck = (tid & 7) * 8;     // 8-col chunk base
    const int vsw = ldr ^ fck;         // swizzled Vt column for this thread

    const short one = (short)0x3F80;   // bf16 1.0
    const bf16x8 ones = { one, one, one, one, one, one, one, one };

    for (int half = 0; half < 2; ++half) {
        const int qb    = (half == 0) ? (7 - blockIdx.x) : blockIdx.x;  // long first
        const int qBase = qb * 256;
        const int wq0   = qBase + wave * 32;  // this wave's first q row

        bf16x8 qf[2][2];
#pragma unroll
        for (int rg = 0; rg < 2; ++rg)
#pragma unroll
            for (int kh = 0; kh < 2; ++kh)
                qf[rg][kh] = *(const bf16x8*)(
                    Q + (size_t)(wq0 + rg * 16 + lrow) * HD + kh * 32 + lq * 8);

        f32x4 o[2][4] = {};
        f32x4 lacc[2] = {};

        float4 ka[2], va[2], kn[2], vn[2];
        {
            const float* Kp = K + (size_t)ldr * HD + fck;
            const float* Vp = V + (size_t)ldr * HD + fck;
            ka[0] = *(const float4*)(Kp); ka[1] = *(const float4*)(Kp + 4);
            va[0] = *(const float4*)(Vp); va[1] = *(const float4*)(Vp + 4);
        }

        const int nkt = 4 * (qb + 1);
        for (int kt = 0; kt < nkt; ++kt) {
            ldsbar();  // prior iter's Ks/Vt fragment reads done (LDS-only drain)
            *(u16x8*)&Ks[ldr][fck] = pack8(ka[0], ka[1]);
            Vt[fck + 0][vsw] = f2bf(va[0].x);
            Vt[fck + 1][vsw] = f2bf(va[0].y);
            Vt[fck + 2][vsw] = f2bf(va[0].z);
            Vt[fck + 3][vsw] = f2bf(va[0].w);
            Vt[fck + 4][vsw] = f2bf(va[1].x);
            Vt[fck + 5][vsw] = f2bf(va[1].y);
            Vt[fck + 6][vsw] = f2bf(va[1].z);
            Vt[fck + 7][vsw] = f2bf(va[1].w);
            if (kt + 1 < nkt) {  // prefetch next K/V tile — stays in flight now
                const float* Kp = K + (size_t)((kt + 1) * 64 + ldr) * HD + fck;
                const float* Vp = V + (size_t)((kt + 1) * 64 + ldr) * HD + fck;
                kn[0] = *(const float4*)(Kp); kn[1] = *(const float4*)(Kp + 4);
                vn[0] = *(const float4*)(Vp); vn[1] = *(const float4*)(Vp + 4);
            }
            ldsbar();  // Ks/Vt visible; prefetch NOT drained

            const int kbase = kt * 64;
            if (kbase <= wq0 + 31) {
                bf16x8 kf[4][2];
#pragma unroll
                for (int nt = 0; nt < 4; ++nt) {
                    kf[nt][0] = *(const bf16x8*)&Ks[nt * 16 + lrow][lq * 8];
                    kf[nt][1] = *(const bf16x8*)&Ks[nt * 16 + lrow][32 + lq * 8];
                }

#pragma unroll
                for (int rg = 0; rg < 2; ++rg) {
                    f32x4 s[4];
#pragma unroll
                    for (int nt = 0; nt < 4; ++nt) {
                        f32x4 t = {};
                        t = __builtin_amdgcn_mfma_f32_16x16x32_bf16(qf[rg][0], kf[nt][0], t, 0, 0, 0);
                        t = __builtin_amdgcn_mfma_f32_16x16x32_bf16(qf[rg][1], kf[nt][1], t, 0, 0, 0);
                        s[nt] = t;
                    }
#pragma unroll
                    for (int nt = 0; nt < 4; ++nt)
#pragma unroll
                        for (int rr = 0; rr < 4; ++rr) s[nt][rr] *= 0.125f;
                    const int rq = wq0 + rg * 16;
                    if (kbase + 63 > rq) {
#pragma unroll
                        for (int nt = 0; nt < 4; ++nt)
#pragma unroll
                            for (int rr = 0; rr < 4; ++rr)
                                if (kbase + nt * 16 + lrow > rq + lq * 4 + rr)
                                    s[nt][rr] = -1e30f;
                    }
#pragma unroll
                    for (int nt = 0; nt < 4; ++nt)
#pragma unroll
                        for (int rr = 0; rr < 4; ++rr) {
                            const int pr = wave * 32 + rg * 16 + lq * 4 + rr;
                            const int pc = (nt * 16 + lrow) ^ (8 * ((lq * 4 + rr) & 7));
                            Ps[pr][pc] = f2bf(__expf(s[nt][rr]));
                        }
                }

                bf16x8 pf[2][2];
#pragma unroll
                for (int rg = 0; rg < 2; ++rg) {
                    const int pr  = wave * 32 + rg * 16 + lrow;
                    const int swz = 8 * (lrow & 7);
                    pf[rg][0] = *(const bf16x8*)&Ps[pr][(lq * 8) ^ swz];
                    pf[rg][1] = *(const bf16x8*)&Ps[pr][(32 + lq * 8) ^ swz];
                    lacc[rg] = __builtin_amdgcn_mfma_f32_16x16x32_bf16(pf[rg][0], ones, lacc[rg], 0, 0, 0);
                    lacc[rg] = __builtin_amdgcn_mfma_f32_16x16x32_bf16(pf[rg][1], ones, lacc[rg], 0, 0, 0);
                }
#pragma unroll
                for (int nt = 0; nt < 4; ++nt) {
                    const int row  = nt * 16 + lrow;
                    const int cswz = (row >> 3) << 3;
                    bf16x8 vf0 = *(const bf16x8*)&Vt[row][(lq * 8) ^ cswz];
                    bf16x8 vf1 = *(const bf16x8*)&Vt[row][(32 + lq * 8) ^ cswz];
#pragma unroll
                    for (int rg = 0; rg < 2; ++rg) {
                        o[rg][nt] = __builtin_amdgcn_mfma_f32_16x16x32_bf16(pf[rg][0], vf0, o[rg][nt], 0, 0, 0);
                        o[rg][nt] = __builtin_amdgcn_mfma_f32_16x16x32_bf16(pf[rg][1], vf1, o[rg][nt], 0, 0, 0);
                    }
                }
            }

            ka[0] = kn[0]; ka[1] = kn[1]; va[0] = vn[0]; va[1] = vn[1];
        }

#pragma unroll
        for (int rg = 0; rg < 2; ++rg) {
            float linv[4];
#pragma unroll
            for (int rr = 0; rr < 4; ++rr) linv[rr] = 1.0f / lacc[rg][rr];
#pragma unroll
            for (int nt = 0; nt < 4; ++nt) {
                const int d = nt * 16 + lrow;
#pragma unroll
                for (int rr = 0; rr < 4; ++rr) {
                    const int srow = wq0 + rg * 16 + lq * 4 + rr;
                    size_t idx = ((size_t)b * SS + srow) * HH + h * HD + d;
                    ctx[idx] = f2bf(o[rg][nt][rr] * linv[rr]);
                }
            }
        }
    }
}

extern "C" void kernel_launch(void* const* d_in, const int* in_sizes, int n_in,
                              void* d_out, int out_size, void* d_ws, size_t ws_size,
                              hipStream_t stream)
{
    const float* hs = (const float*)d_in[0];
    const float* Wq = (const float*)d_in[1];
    const float* bq = (const float*)d_in[2];
    const float* Wk = (const float*)d_in[3];
    const float* bk = (const float*)d_in[4];
    const float* Wv = (const float*)d_in[5];
    const float* bv = (const float*)d_in[6];
    const float* Wp = (const float*)d_in[7];
    const float* bp = (const float*)d_in[8];

    float* out  = (float*)d_out;
    float* kout = out + (size_t)M * HH;   // K fp32 (final)
    float* vout = kout + (size_t)M * HH;  // V fp32 (final)
    // scratch inside the out region (dead before proj overwrites it):
    unsigned short* WTbuf = (unsigned short*)d_out;                   // 6.3 MB, dead after qkv
    unsigned short* qbuf  = (unsigned short*)d_out + (size_t)M * HH;  // 16.8 MB, dead after attn
    // ws scratch: Xbf lives until qkv; ctx (attn output) reuses the same bytes
    unsigned short* Xbf = (unsigned short*)d_ws;                      // 16.8 MB
    unsigned short* ctx = (unsigned short*)d_ws;                      // 16.8 MB (after qkv)
    const size_t wsNeedBF = (size_t)M * HH * 2 + (size_t)HH * HH * 2;
    const bool   wsBig    = ws_size >= wsNeedBF;
    unsigned short* WTp = (unsigned short*)d_ws + (size_t)M * HH;     // 2.1 MB, iff wsBig

    prep_k<<<dim3(M * HH / (256 * 8), 1, 5), 256, 0, stream>>>(
        hs, Wq, Wk, Wv, Wp, Xbf, WTbuf, WTp, wsBig ? 1 : 0);
    qkv_gemm<<<dim3(M / 128, HH / 128, 3), 256, 0, stream>>>(
        Xbf, WTbuf, bq, bk, bv, qbuf, kout, vout);
    attn_k<<<dim3(4, BB * NH), 512, 0, stream>>>(qbuf, kout, vout, ctx);
    if (wsBig)
        proj_bf<<<dim3(M / 128, HH / 128), 256, 0, stream>>>(ctx, WTp, bp, out);
    else
        proj_gemm<<<dim3(M / 128, HH / 128), 256, 0, stream>>>(ctx, Wp, bp, out);
}

// Round 5
// 305.619 us; speedup vs baseline: 1.0867x; 1.0867x over previous
//
#include <hip/hip_runtime.h>

constexpr int BB = 4, SS = 2048, HH = 1024, NH = 16, HD = 64;
constexpr int M = BB * SS;  // 8192 rows for all GEMMs

typedef short          bf16x8 __attribute__((ext_vector_type(8)));
typedef unsigned short u16x8  __attribute__((ext_vector_type(8)));
typedef float          f32x4  __attribute__((ext_vector_type(4)));

// round-half-up bf16 cvt (differs from RNE only on exact ties)
__device__ __forceinline__ unsigned short f2bf(float f) {
    union { float f; unsigned u; } c; c.f = f;
    return (unsigned short)((c.u + 0x8000u) >> 16);
}
__device__ __forceinline__ unsigned packbf2(float lo, float hi) {
    return (unsigned)f2bf(lo) | ((unsigned)f2bf(hi) << 16);
}
__device__ __forceinline__ u16x8 pack8(const float4& x, const float4& y) {
    u16x8 r = { f2bf(x.x), f2bf(x.y), f2bf(x.z), f2bf(x.w),
                f2bf(y.x), f2bf(y.y), f2bf(y.z), f2bf(y.w) };
    return r;
}

// global -> LDS direct DMA, 16B per lane.
__device__ __forceinline__ void gld_lds16(const unsigned short* g, unsigned short* l) {
    __builtin_amdgcn_global_load_lds(
        (const __attribute__((address_space(1))) unsigned int*)(const void*)g,
        (__attribute__((address_space(3))) unsigned int*)(void*)l,
        16, 0, 0);
}

// Workgroup barrier draining ONLY LDS (lgkmcnt): global prefetch loads stay
// in flight across the barrier.
__device__ __forceinline__ void ldsbar() {
    __builtin_amdgcn_sched_barrier(0);
    asm volatile("s_waitcnt lgkmcnt(0)" ::: "memory");
    __builtin_amdgcn_s_barrier();
    __builtin_amdgcn_sched_barrier(0);
}

// ---------------------------------------------------------------------------
// Fused prep: z=0 -> X fp32->bf16 (4096 blocks); z=1..4 -> Wq/Wk/Wv/Wp
// fp32 [k][n] -> bf16 transposed [n][k] via 64x64 LDS tiles (256 blocks).
// ---------------------------------------------------------------------------
__global__ __launch_bounds__(256) void prep_k(
    const float* __restrict__ hs,
    const float* __restrict__ Wq, const float* __restrict__ Wk,
    const float* __restrict__ Wv, const float* __restrict__ Wp,
    unsigned short* __restrict__ Xb, unsigned short* __restrict__ WT,
    unsigned short* __restrict__ WTp, const int doWp)
{
    __shared__ __attribute__((aligned(16))) unsigned short T[64][72];

    if (blockIdx.z == 0) {
        const size_t i = ((size_t)blockIdx.x * 256 + threadIdx.x) * 8;
        float4 x0 = *(const float4*)(hs + i);
        float4 x1 = *(const float4*)(hs + i + 4);
        *(u16x8*)(Xb + i) = pack8(x0, x1);
        return;
    }
    if (blockIdx.x >= 256) return;
    const int z = blockIdx.z - 1;
    if (z == 3 && !doWp) return;
    const float* W = (z == 0) ? Wq : (z == 1) ? Wk : (z == 2) ? Wv : Wp;
    unsigned short* D = (z == 3) ? WTp : WT + (size_t)z * HH * HH;

    const int tid = threadIdx.x;
    const int kB = (blockIdx.x & 15) * 64, nB = (blockIdx.x >> 4) * 64;
    const int r = tid >> 2, c0 = (tid & 3) * 16;
#pragma unroll
    for (int j = 0; j < 4; ++j) {
        float4 w = *(const float4*)(W + (size_t)(kB + r) * HH + nB + c0 + j * 4);
        T[c0 + j * 4 + 0][r] = f2bf(w.x);
        T[c0 + j * 4 + 1][r] = f2bf(w.y);
        T[c0 + j * 4 + 2][r] = f2bf(w.z);
        T[c0 + j * 4 + 3][r] = f2bf(w.w);
    }
    __syncthreads();
    *(u16x8*)(D + (size_t)(nB + r) * HH + kB + c0)     = *(const u16x8*)&T[r][c0];
    *(u16x8*)(D + (size_t)(nB + r) * HH + kB + c0 + 8) = *(const u16x8*)&T[r][c0 + 8];
}

// ---------------------------------------------------------------------------
// QKV GEMM, m97 structure: 128x128 tile, BK=32, both operands bf16 staged
// via global_load_lds (width 16), 2 barriers per K-step.  Direct scattered
// epilogue (R3 form — measured faster than LDS-restaged coalescing).
// Q is written PRE-SCALED by 0.125 (exact exponent shift, bit-identical
// scores) so attn skips the per-element scale.
// ---------------------------------------------------------------------------
__global__ __launch_bounds__(256) void qkv_gemm(
    const unsigned short* __restrict__ Xb, const unsigned short* __restrict__ WT,
    const float* __restrict__ bq, const float* __restrict__ bk, const float* __restrict__ bv,
    unsigned short* __restrict__ Qd, float* __restrict__ Kd, float* __restrict__ Vd)
{
    const int z = blockIdx.z;
    const unsigned short* Wg = WT + (size_t)z * HH * HH;
    const float* bias = (z == 0) ? bq : (z == 1) ? bk : bv;

    __shared__ __attribute__((aligned(16))) unsigned short As[128 * 32];
    __shared__ __attribute__((aligned(16))) unsigned short Bs[128 * 32];

    const int tid  = threadIdx.x;
    const int wave = tid >> 6, lane = tid & 63;
    const int lrow = lane & 15, lq = lane >> 4;
    const int rQ = (wave >> 1) * 64, cQ = (wave & 1) * 64;
    const int mBase = blockIdx.x * 128, nBase = blockIdx.y * 128;

    f32x4 acc[4][4] = {};

    const int srow = lane >> 2, scol = (lane & 3) * 8;
    const int c0 = wave * 2, c1 = wave * 2 + 1;

    const unsigned short* ga0 = Xb + (size_t)(mBase + c0 * 16 + srow) * HH + scol;
    const unsigned short* ga1 = Xb + (size_t)(mBase + c1 * 16 + srow) * HH + scol;
    const unsigned short* gb0 = Wg + (size_t)(nBase + c0 * 16 + srow) * HH + scol;
    const unsigned short* gb1 = Wg + (size_t)(nBase + c1 * 16 + srow) * HH + scol;
    unsigned short* la0 = &As[c0 * 512];
    unsigned short* la1 = &As[c1 * 512];
    unsigned short* lb0 = &Bs[c0 * 512];
    unsigned short* lb1 = &Bs[c1 * 512];

    for (int k0 = 0; k0 < HH; k0 += 32) {
        __syncthreads();  // prior iter's fragment reads done
        gld_lds16(ga0 + k0, la0);
        gld_lds16(ga1 + k0, la1);
        gld_lds16(gb0 + k0, lb0);
        gld_lds16(gb1 + k0, lb1);
        __syncthreads();  // staging complete

        bf16x8 af[4], bf[4];
#pragma unroll
        for (int i = 0; i < 4; ++i)
            af[i] = *(const bf16x8*)&As[(rQ + i * 16 + lrow) * 32 + lq * 8];
#pragma unroll
        for (int j = 0; j < 4; ++j)
            bf[j] = *(const bf16x8*)&Bs[(cQ + j * 16 + lrow) * 32 + lq * 8];
#pragma unroll
        for (int i = 0; i < 4; ++i)
#pragma unroll
            for (int j = 0; j < 4; ++j)
                acc[i][j] = __builtin_amdgcn_mfma_f32_16x16x32_bf16(af[i], bf[j], acc[i][j], 0, 0, 0);
    }

#pragma unroll
    for (int j = 0; j < 4; ++j) {
        int   n  = nBase + cQ + j * 16 + lrow;
        float bv = bias[n];
        int   h = n >> 6, d = n & 63;
#pragma unroll
        for (int i = 0; i < 4; ++i) {
#pragma unroll
            for (int r = 0; r < 4; ++r) {
                int   m   = mBase + rQ + i * 16 + lq * 4 + r;
                float val = acc[i][j][r] + bv;
                int   b = m >> 11, s = m & (SS - 1);
                size_t idx = ((size_t)(b * NH + h) * SS + s) * HD + d;
                if (z == 0)      Qd[idx] = f2bf(val * 0.125f);  // pre-scaled Q
                else if (z == 1) Kd[idx] = val;
                else             Vd[idx] = val;
            }
        }
    }
}

// ---------------------------------------------------------------------------
// Output projection, m97 structure, direct epilogue (R3 form).
// ---------------------------------------------------------------------------
__global__ __launch_bounds__(256) void proj_bf(
    const unsigned short* __restrict__ Xc, const unsigned short* __restrict__ WTp,
    const float* __restrict__ bias, float* __restrict__ dst)
{
    __shared__ __attribute__((aligned(16))) unsigned short As[128 * 32];
    __shared__ __attribute__((aligned(16))) unsigned short Bs[128 * 32];

    const int tid  = threadIdx.x;
    const int wave = tid >> 6, lane = tid & 63;
    const int lrow = lane & 15, lq = lane >> 4;
    const int rQ = (wave >> 1) * 64, cQ = (wave & 1) * 64;
    const int mBase = blockIdx.x * 128, nBase = blockIdx.y * 128;

    f32x4 acc[4][4] = {};

    const int srow = lane >> 2, scol = (lane & 3) * 8;
    const int c0 = wave * 2, c1 = wave * 2 + 1;

    const unsigned short* ga0 = Xc  + (size_t)(mBase + c0 * 16 + srow) * HH + scol;
    const unsigned short* ga1 = Xc  + (size_t)(mBase + c1 * 16 + srow) * HH + scol;
    const unsigned short* gb0 = WTp + (size_t)(nBase + c0 * 16 + srow) * HH + scol;
    const unsigned short* gb1 = WTp + (size_t)(nBase + c1 * 16 + srow) * HH + scol;
    unsigned short* la0 = &As[c0 * 512];
    unsigned short* la1 = &As[c1 * 512];
    unsigned short* lb0 = &Bs[c0 * 512];
    unsigned short* lb1 = &Bs[c1 * 512];

    for (int k0 = 0; k0 < HH; k0 += 32) {
        __syncthreads();
        gld_lds16(ga0 + k0, la0);
        gld_lds16(ga1 + k0, la1);
        gld_lds16(gb0 + k0, lb0);
        gld_lds16(gb1 + k0, lb1);
        __syncthreads();

        bf16x8 af[4], bf[4];
#pragma unroll
        for (int i = 0; i < 4; ++i)
            af[i] = *(const bf16x8*)&As[(rQ + i * 16 + lrow) * 32 + lq * 8];
#pragma unroll
        for (int j = 0; j < 4; ++j)
            bf[j] = *(const bf16x8*)&Bs[(cQ + j * 16 + lrow) * 32 + lq * 8];
#pragma unroll
        for (int i = 0; i < 4; ++i)
#pragma unroll
            for (int j = 0; j < 4; ++j)
                acc[i][j] = __builtin_amdgcn_mfma_f32_16x16x32_bf16(af[i], bf[j], acc[i][j], 0, 0, 0);
    }

#pragma unroll
    for (int j = 0; j < 4; ++j) {
        int   n  = nBase + cQ + j * 16 + lrow;
        float bv = bias[n];
#pragma unroll
        for (int i = 0; i < 4; ++i)
#pragma unroll
            for (int r = 0; r < 4; ++r) {
                int m = mBase + rQ + i * 16 + lq * 4 + r;
                dst[(size_t)m * HH + n] = acc[i][j][r] + bv;
            }
    }
}

// ---------------------------------------------------------------------------
// Fallback output projection (W fp32 transposed in-kernel) for small ws.
// ---------------------------------------------------------------------------
__global__ __launch_bounds__(256) void proj_gemm(
    const unsigned short* __restrict__ X, const float* __restrict__ Wm,
    const float* __restrict__ bias, float* __restrict__ dst)
{
    __shared__ __attribute__((aligned(16))) unsigned short Al[128][40];
    __shared__ __attribute__((aligned(16))) unsigned short Wt[128][40];

    const int tid  = threadIdx.x;
    const int wave = tid >> 6, lane = tid & 63;
    const int lrow = lane & 15, lq = lane >> 4;
    const int rQ = (wave >> 1) * 64, cQ = (wave & 1) * 64;
    const int mBase = blockIdx.x * 128, nBase = blockIdx.y * 128;

    f32x4 acc[4][4] = {};

    const int arow = tid >> 1, acol = (tid & 1) * 16;
    const int wcol = (tid & 15) * 8, wrow = (tid >> 4) * 2;

    const unsigned short* Ap = X + (size_t)(mBase + arow) * HH + acol;
    const float*          Wp = Wm + (size_t)wrow * HH + nBase + wcol;

    u16x8 a0, a1, a0n, a1n;
    float4 w0a, w0b, w1a, w1b, w0an, w0bn, w1an, w1bn;
    a0 = *(const u16x8*)Ap; a1 = *(const u16x8*)(Ap + 8);
    w0a = *(const float4*)(Wp);      w0b = *(const float4*)(Wp + 4);
    w1a = *(const float4*)(Wp + HH); w1b = *(const float4*)(Wp + HH + 4);
    Ap += 32; Wp += (size_t)32 * HH;

    for (int k0 = 0; k0 < HH; k0 += 32) {
        __syncthreads();
        *(u16x8*)&Al[arow][acol]     = a0;
        *(u16x8*)&Al[arow][acol + 8] = a1;
        *(unsigned*)&Wt[wcol + 0][wrow] = packbf2(w0a.x, w1a.x);
        *(unsigned*)&Wt[wcol + 1][wrow] = packbf2(w0a.y, w1a.y);
        *(unsigned*)&Wt[wcol + 2][wrow] = packbf2(w0a.z, w1a.z);
        *(unsigned*)&Wt[wcol + 3][wrow] = packbf2(w0a.w, w1a.w);
        *(unsigned*)&Wt[wcol + 4][wrow] = packbf2(w0b.x, w1b.x);
        *(unsigned*)&Wt[wcol + 5][wrow] = packbf2(w0b.y, w1b.y);
        *(unsigned*)&Wt[wcol + 6][wrow] = packbf2(w0b.z, w1b.z);
        *(unsigned*)&Wt[wcol + 7][wrow] = packbf2(w0b.w, w1b.w);
        if (k0 + 32 < HH) {
            a0n = *(const u16x8*)Ap; a1n = *(const u16x8*)(Ap + 8);
            w0an = *(const float4*)(Wp);      w0bn = *(const float4*)(Wp + 4);
            w1an = *(const float4*)(Wp + HH); w1bn = *(const float4*)(Wp + HH + 4);
            Ap += 32; Wp += (size_t)32 * HH;
        }
        __syncthreads();

        bf16x8 af[4], bf[4];
#pragma unroll
        for (int i = 0; i < 4; ++i) af[i] = *(const bf16x8*)&Al[rQ + i * 16 + lrow][lq * 8];
#pragma unroll
        for (int j = 0; j < 4; ++j) bf[j] = *(const bf16x8*)&Wt[cQ + j * 16 + lrow][lq * 8];
#pragma unroll
        for (int i = 0; i < 4; ++i)
#pragma unroll
            for (int j = 0; j < 4; ++j)
                acc[i][j] = __builtin_amdgcn_mfma_f32_16x16x32_bf16(af[i], bf[j], acc[i][j], 0, 0, 0);

        a0 = a0n; a1 = a1n;
        w0a = w0an; w0b = w0bn; w1a = w1an; w1b = w1bn;
    }

#pragma unroll
    for (int j = 0; j < 4; ++j) {
        int   n  = nBase + cQ + j * 16 + lrow;
        float bv = bias[n];
#pragma unroll
        for (int i = 0; i < 4; ++i)
#pragma unroll
            for (int r = 0; r < 4; ++r) {
                int m = mBase + rQ + i * 16 + lq * 4 + r;
                dst[(size_t)m * HH + n] = acc[i][j][r] + bv;
            }
    }
}

// ---------------------------------------------------------------------------
// Causal flash attention v5: QBLK=256 / 8 waves / KVBLK=128 (two 64-row
// sub-tiles per barrier pair, each using the R3-verified bank-free mapping).
// Barrier pairs per block: 36 -> 18.  Q pre-scaled by 0.125 in qkv (no
// per-tile scale).  XCD co-location: the 4 blocks sharing one (b,h)'s K/V
// map to the same XCD (bid%8) so K+V (2 MB) lives in that XCD's 4 MB L2.
// LDS 67 KB (gfx950 supports up to 160 KB/WG).
// ---------------------------------------------------------------------------
__global__ __launch_bounds__(512, 2) void attn_k(
    const unsigned short* __restrict__ Qb, const float* __restrict__ Kb,
    const float* __restrict__ Vb, unsigned short* __restrict__ ctx)
{
    __shared__ __attribute__((aligned(16))) unsigned short Ps[256][64];   // swizzled
    __shared__ __attribute__((aligned(16))) unsigned short Ks[128][72];
    __shared__ __attribute__((aligned(16))) unsigned short Vt[64][136];   // Vt[d][s^swz]

    const int tid  = threadIdx.x;
    const int wave = tid >> 6, lane = tid & 63;
    const int lrow = lane & 15, lq = lane >> 4;

    // XCD co-location remap: 4 q-blocks of one bh on one XCD
    const int bid = blockIdx.x;               // 0..255
    const int bh  = (bid & 7) * 8 + (bid >> 5);
    const int xq  = (bid >> 3) & 3;           // 0..3 (q pair index)
    const int b = bh >> 4, h = bh & 15;

    const unsigned short* Q = Qb + (size_t)bh * SS * HD;
    const float*          K = Kb + (size_t)bh * SS * HD;
    const float*          V = Vb + (size_t)bh * SS * HD;

    const int ldr = tid >> 3;          // sub-tile row 0..63
    const int fck = (tid & 7) * 8;     // 8-col chunk base
    const int vsw = ldr ^ fck;         // swizzled Vt column (sub-tile A)

    const short one = (short)0x3F80;   // bf16 1.0
    const bf16x8 ones = { one, one, one, one, one, one, one, one };

    for (int half = 0; half < 2; ++half) {
        const int qb    = (half == 0) ? (7 - xq) : xq;  // long first
        const int qBase = qb * 256;
        const int wq0   = qBase + wave * 32;  // this wave's first q row

        bf16x8 qf[2][2];
#pragma unroll
        for (int rg = 0; rg < 2; ++rg)
#pragma unroll
            for (int kh = 0; kh < 2; ++kh)
                qf[rg][kh] = *(const bf16x8*)(
                    Q + (size_t)(wq0 + rg * 16 + lrow) * HD + kh * 32 + lq * 8);

        f32x4 o[2][4] = {};
        f32x4 lacc[2] = {};

        float4 ka[4], va[4], kn[4], vn[4];
        {
            const float* Kp0 = K + (size_t)ldr * HD + fck;
            const float* Kp1 = K + (size_t)(64 + ldr) * HD + fck;
            const float* Vp0 = V + (size_t)ldr * HD + fck;
            const float* Vp1 = V + (size_t)(64 + ldr) * HD + fck;
            ka[0] = *(const float4*)Kp0; ka[1] = *(const float4*)(Kp0 + 4);
            ka[2] = *(const float4*)Kp1; ka[3] = *(const float4*)(Kp1 + 4);
            va[0] = *(const float4*)Vp0; va[1] = *(const float4*)(Vp0 + 4);
            va[2] = *(const float4*)Vp1; va[3] = *(const float4*)(Vp1 + 4);
        }

        const int nkt = 2 * (qb + 1);  // 128-wide tiles
        for (int kt = 0; kt < nkt; ++kt) {
            ldsbar();  // prior iter's Ks/Vt fragment reads done (LDS-only drain)
            *(u16x8*)&Ks[ldr][fck]      = pack8(ka[0], ka[1]);
            *(u16x8*)&Ks[64 + ldr][fck] = pack8(ka[2], ka[3]);
            Vt[fck + 0][vsw] = f2bf(va[0].x);
            Vt[fck + 1][vsw] = f2bf(va[0].y);
            Vt[fck + 2][vsw] = f2bf(va[0].z);
            Vt[fck + 3][vsw] = f2bf(va[0].w);
            Vt[fck + 4][vsw] = f2bf(va[1].x);
            Vt[fck + 5][vsw] = f2bf(va[1].y);
            Vt[fck + 6][vsw] = f2bf(va[1].z);
            Vt[fck + 7][vsw] = f2bf(va[1].w);
            Vt[fck + 0][64 + vsw] = f2bf(va[2].x);
            Vt[fck + 1][64 + vsw] = f2bf(va[2].y);
            Vt[fck + 2][64 + vsw] = f2bf(va[2].z);
            Vt[fck + 3][64 + vsw] = f2bf(va[2].w);
            Vt[fck + 4][64 + vsw] = f2bf(va[3].x);
            Vt[fck + 5][64 + vsw] = f2bf(va[3].y);
            Vt[fck + 6][64 + vsw] = f2bf(va[3].z);
            Vt[fck + 7][64 + vsw] = f2bf(va[3].w);
            if (kt + 1 < nkt) {  // prefetch next 128-tile; stays in flight
                const int rb = (kt + 1) * 128;
                const float* Kp0 = K + (size_t)(rb + ldr) * HD + fck;
                const float* Kp1 = K + (size_t)(rb + 64 + ldr) * HD + fck;
                const float* Vp0 = V + (size_t)(rb + ldr) * HD + fck;
                const float* Vp1 = V + (size_t)(rb + 64 + ldr) * HD + fck;
                kn[0] = *(const float4*)Kp0; kn[1] = *(const float4*)(Kp0 + 4);
                kn[2] = *(const float4*)Kp1; kn[3] = *(const float4*)(Kp1 + 4);
                vn[0] = *(const float4*)Vp0; vn[1] = *(const float4*)(Vp0 + 4);
                vn[2] = *(const float4*)Vp1; vn[3] = *(const float4*)(Vp1 + 4);
            }
            ldsbar();  // Ks/Vt visible; prefetch NOT drained

#pragma unroll
            for (int hh = 0; hh < 2; ++hh) {
                const int kbase = kt * 128 + hh * 64;
                if (kbase > wq0 + 31) break;  // wave-uniform: fully masked
                const int kro = hh * 64;

                bf16x8 kf[4][2];
#pragma unroll
                for (int nt = 0; nt < 4; ++nt) {
                    kf[nt][0] = *(const bf16x8*)&Ks[kro + nt * 16 + lrow][lq * 8];
                    kf[nt][1] = *(const bf16x8*)&Ks[kro + nt * 16 + lrow][32 + lq * 8];
                }

#pragma unroll
                for (int rg = 0; rg < 2; ++rg) {
                    f32x4 s[4];
                    __builtin_amdgcn_s_setprio(1);
#pragma unroll
                    for (int nt = 0; nt < 4; ++nt) {
                        f32x4 t = {};
                        t = __builtin_amdgcn_mfma_f32_16x16x32_bf16(qf[rg][0], kf[nt][0], t, 0, 0, 0);
                        t = __builtin_amdgcn_mfma_f32_16x16x32_bf16(qf[rg][1], kf[nt][1], t, 0, 0, 0);
                        s[nt] = t;
                    }
                    __builtin_amdgcn_s_setprio(0);
                    const int rq = wq0 + rg * 16;
                    if (kbase + 63 > rq) {  // diagonal region -> element mask
#pragma unroll
                        for (int nt = 0; nt < 4; ++nt)
#pragma unroll
                            for (int rr = 0; rr < 4; ++rr)
                                if (kbase + nt * 16 + lrow > rq + lq * 4 + rr)
                                    s[nt][rr] = -1e30f;
                    }
#pragma unroll
                    for (int nt = 0; nt < 4; ++nt)
#pragma unroll
                        for (int rr = 0; rr < 4; ++rr) {
                            const int pr = wave * 32 + rg * 16 + lq * 4 + rr;
                            const int pc = (nt * 16 + lrow) ^ (8 * ((lq * 4 + rr) & 7));
                            Ps[pr][pc] = f2bf(__expf(s[nt][rr]));
                        }
                }

                bf16x8 pf[2][2];
#pragma unroll
                for (int rg = 0; rg < 2; ++rg) {
                    const int pr  = wave * 32 + rg * 16 + lrow;
                    const int swz = 8 * (lrow & 7);
                    pf[rg][0] = *(const bf16x8*)&Ps[pr][(lq * 8) ^ swz];
                    pf[rg][1] = *(const bf16x8*)&Ps[pr][(32 + lq * 8) ^ swz];
                    lacc[rg] = __builtin_amdgcn_mfma_f32_16x16x32_bf16(pf[rg][0], ones, lacc[rg], 0, 0, 0);
                    lacc[rg] = __builtin_amdgcn_mfma_f32_16x16x32_bf16(pf[rg][1], ones, lacc[rg], 0, 0, 0);
                }
                __builtin_amdgcn_s_setprio(1);
#pragma unroll
                for (int nt = 0; nt < 4; ++nt) {
                    const int row  = nt * 16 + lrow;
                    const int cswz = (row >> 3) << 3;
                    bf16x8 vf0 = *(const bf16x8*)&Vt[row][kro + ((lq * 8) ^ cswz)];
                    bf16x8 vf1 = *(const bf16x8*)&Vt[row][kro + (((32 + lq * 8)) ^ cswz)];
#pragma unroll
                    for (int rg = 0; rg < 2; ++rg) {
                        o[rg][nt] = __builtin_amdgcn_mfma_f32_16x16x32_bf16(pf[rg][0], vf0, o[rg][nt], 0, 0, 0);
                        o[rg][nt] = __builtin_amdgcn_mfma_f32_16x16x32_bf16(pf[rg][1], vf1, o[rg][nt], 0, 0, 0);
                    }
                }
                __builtin_amdgcn_s_setprio(0);
            }

#pragma unroll
            for (int c = 0; c < 4; ++c) { ka[c] = kn[c]; va[c] = vn[c]; }
        }

        // epilogue: O /= l, write ctx bf16 as [b, s, h*HD + d]
#pragma unroll
        for (int rg = 0; rg < 2; ++rg) {
            float linv[4];
#pragma unroll
            for (int rr = 0; rr < 4; ++rr) linv[rr] = 1.0f / lacc[rg][rr];
#pragma unroll
            for (int nt = 0; nt < 4; ++nt) {
                const int d = nt * 16 + lrow;
#pragma unroll
                for (int rr = 0; rr < 4; ++rr) {
                    const int srow = wq0 + rg * 16 + lq * 4 + rr;
                    size_t idx = ((size_t)b * SS + srow) * HH + h * HD + d;
                    ctx[idx] = f2bf(o[rg][nt][rr] * linv[rr]);
                }
            }
        }
    }
}

extern "C" void kernel_launch(void* const* d_in, const int* in_sizes, int n_in,
                              void* d_out, int out_size, void* d_ws, size_t ws_size,
                              hipStream_t stream)
{
    const float* hs = (const float*)d_in[0];
    const float* Wq = (const float*)d_in[1];
    const float* bq = (const float*)d_in[2];
    const float* Wk = (const float*)d_in[3];
    const float* bk = (const float*)d_in[4];
    const float* Wv = (const float*)d_in[5];
    const float* bv = (const float*)d_in[6];
    const float* Wp = (const float*)d_in[7];
    const float* bp = (const float*)d_in[8];

    float* out  = (float*)d_out;
    float* kout = out + (size_t)M * HH;   // K fp32 (final)
    float* vout = kout + (size_t)M * HH;  // V fp32 (final)
    // scratch inside the out region (dead before proj overwrites it):
    unsigned short* WTbuf = (unsigned short*)d_out;                   // 6.3 MB, dead after qkv
    unsigned short* qbuf  = (unsigned short*)d_out + (size_t)M * HH;  // 16.8 MB, dead after attn
    // ws scratch: Xbf lives until qkv; ctx (attn output) reuses the same bytes
    unsigned short* Xbf = (unsigned short*)d_ws;                      // 16.8 MB
    unsigned short* ctx = (unsigned short*)d_ws;                      // 16.8 MB (after qkv)
    const size_t wsNeedBF = (size_t)M * HH * 2 + (size_t)HH * HH * 2;
    const bool   wsBig    = ws_size >= wsNeedBF;
    unsigned short* WTp = (unsigned short*)d_ws + (size_t)M * HH;     // 2.1 MB, iff wsBig

    prep_k<<<dim3(M * HH / (256 * 8), 1, 5), 256, 0, stream>>>(
        hs, Wq, Wk, Wv, Wp, Xbf, WTbuf, WTp, wsBig ? 1 : 0);
    qkv_gemm<<<dim3(M / 128, HH / 128, 3), 256, 0, stream>>>(
        Xbf, WTbuf, bq, bk, bv, qbuf, kout, vout);
    attn_k<<<dim3(256), 512, 0, stream>>>(qbuf, kout, vout, ctx);
    if (wsBig)
        proj_bf<<<dim3(M / 128, HH / 128), 256, 0, stream>>>(ctx, WTp, bp, out);
    else
        proj_gemm<<<dim3(M / 128, HH / 128), 256, 0, stream>>>(ctx, Wp, bp, out);
}